// Round 1
// baseline (1451.198 us; speedup 1.0000x reference)
//
#include <hip/hip_runtime.h>

// Problem constants (fixed by the reference).
static constexpr int cT = 1024;   // tokens
static constexpr int cH = 1024;   // hidden
static constexpr int cI = 2816;   // intermediate
static constexpr int cE = 16;     // experts
static constexpr int cK = 4;      // top-k

typedef __attribute__((ext_vector_type(8))) short bf16x8;
typedef __attribute__((ext_vector_type(4))) float f32x4;

__device__ __forceinline__ unsigned f2bf(float f) {
  unsigned u = __float_as_uint(f);
  return (u + 0x7FFFu + ((u >> 16) & 1u)) >> 16;   // RNE f32->bf16
}
__device__ __forceinline__ unsigned pack2(float lo, float hi) {
  return f2bf(lo) | (f2bf(hi) << 16);
}

// ---------------------------------------------------------------- router ----
// One 64-lane wave per token: 16 logits via strided dot + butterfly reduce,
// top-4 selection + renormalized softmax weights (== softmax over top-4 logits).
__global__ __launch_bounds__(64) void router_kernel(
    const float* __restrict__ x, const float* __restrict__ Wg,
    int* __restrict__ topk_id, float* __restrict__ topk_w,
    int* __restrict__ counts) {
  const int t = blockIdx.x;
  const int l = threadIdx.x;

  float xa[16];
#pragma unroll
  for (int i = 0; i < 16; ++i) xa[i] = x[(size_t)t * cH + l + 64 * i];

  float lg[16];
#pragma unroll
  for (int e = 0; e < 16; ++e) {
    float s = 0.f;
#pragma unroll
    for (int i = 0; i < 16; ++i) s += xa[i] * Wg[(size_t)e * cH + l + 64 * i];
#pragma unroll
    for (int d = 1; d < 64; d <<= 1) s += __shfl_xor(s, d);
    lg[e] = s;
  }

  if (l == 0) {
    int ids[4]; float vals[4];
    unsigned taken = 0;
#pragma unroll
    for (int j = 0; j < 4; ++j) {
      float m = -1e30f; int mi = 0;
#pragma unroll
      for (int e = 0; e < 16; ++e) {
        bool better = !((taken >> e) & 1u) && lg[e] > m;
        if (better) { m = lg[e]; mi = e; }
      }
      taken |= 1u << mi; ids[j] = mi; vals[j] = m;
    }
    const float mx = vals[0];
    float s = 0.f;
#pragma unroll
    for (int j = 0; j < 4; ++j) { vals[j] = __expf(vals[j] - mx); s += vals[j]; }
    const float inv = 1.f / s;
#pragma unroll
    for (int j = 0; j < 4; ++j) {
      topk_id[t * 4 + j] = ids[j];
      topk_w[t * 4 + j] = vals[j] * inv;
      atomicAdd(&counts[ids[j]], 1);
    }
  }
}

__global__ void scan_kernel(const int* __restrict__ counts,
                            int* __restrict__ offsets) {
  if (threadIdx.x == 0 && blockIdx.x == 0) {
    int acc = 0;
    for (int e = 0; e < cE; ++e) { offsets[e] = acc; acc += counts[e]; }
    offsets[cE] = acc;
  }
}

__global__ __launch_bounds__(256) void scatter_kernel(
    const int* __restrict__ topk_id, const float* __restrict__ topk_w,
    const int* __restrict__ offsets, int* __restrict__ cursor,
    int* __restrict__ pair_token, float* __restrict__ pair_w) {
  const int i = blockIdx.x * 256 + threadIdx.x;   // 0..4095
  const int t = i >> 2;
  const int e = topk_id[i];
  const int pos = offsets[e] + atomicAdd(&cursor[e], 1);
  pair_token[pos] = t;
  pair_w[pos] = topk_w[i];
}

// ---------------------------------------------------------------- gate+up ---
// Per block: expert e, 32 pair-rows (m-tile), 64 intermediate cols (n-tile).
// K-loop over H in steps of 32 with bf16 MFMA. W staged f32->bf16 into LDS
// laid out [k/8][n][k%8] so B-frags are contiguous 16B ds_read_b128.
__global__ __launch_bounds__(256) void gateup_kernel(
    const float* __restrict__ x, const float* __restrict__ gw,
    const float* __restrict__ uw, const int* __restrict__ offsets,
    const int* __restrict__ pair_token, unsigned short* __restrict__ act) {
  const int e = blockIdx.z;
  const int off = offsets[e];
  const int n_e = offsets[e + 1] - off;
  const int mt = blockIdx.x;
  if (mt * 32 >= n_e) return;
  const int nb = blockIdx.y * 64;
  const int tid = threadIdx.x;

  __shared__ unsigned sA[32 * 20];   // [row][k/2], row stride 20 uints (80B)
  __shared__ unsigned sG[1024];      // [k/8][n][k%8] as bf16, uint-packed
  __shared__ unsigned sU[1024];

  // A staging assignment: two rows per thread (ra, ra+16), float2 slot k2.
  const int ra = tid >> 4;
  const int k2 = tid & 15;
  int tokA0 = -1, tokA1 = -1;
  if (mt * 32 + ra < n_e)      tokA0 = pair_token[off + mt * 32 + ra];
  if (mt * 32 + ra + 16 < n_e) tokA1 = pair_token[off + mt * 32 + ra + 16];

  const size_t ebase = (size_t)e * cH * cI;
  const float* gwp = gw + ebase + nb;
  const float* uwp = uw + ebase + nb;

  const int nW = tid & 63;    // W staging: column
  const int kp0 = tid >> 6;   // W staging: k-pair base (adds 4 per it)

  const int w = tid >> 6, l = tid & 63;
  const int rw = (w >> 1) * 16;   // wave row base
  const int cw = (w & 1) * 32;    // wave col base

  f32x4 ag0 = {0.f, 0.f, 0.f, 0.f}, ag1 = {0.f, 0.f, 0.f, 0.f};
  f32x4 au0 = {0.f, 0.f, 0.f, 0.f}, au1 = {0.f, 0.f, 0.f, 0.f};

  for (int kt = 0; kt < cH / 32; ++kt) {
    // stage A (gathered x rows, f32 -> bf16)
    {
      float2 v0 = make_float2(0.f, 0.f), v1 = make_float2(0.f, 0.f);
      if (tokA0 >= 0)
        v0 = *(const float2*)(x + (size_t)tokA0 * cH + kt * 32 + k2 * 2);
      if (tokA1 >= 0)
        v1 = *(const float2*)(x + (size_t)tokA1 * cH + kt * 32 + k2 * 2);
      sA[ra * 20 + k2] = pack2(v0.x, v0.y);
      sA[(ra + 16) * 20 + k2] = pack2(v1.x, v1.y);
    }
    // stage gate/up weights (f32 -> bf16, transposed k-grouping)
#pragma unroll
    for (int it = 0; it < 4; ++it) {
      const int kpi = kp0 + 4 * it;   // 0..15 -> k = 2*kpi
      const size_t base = (size_t)(kt * 32 + 2 * kpi) * cI + nW;
      const float g0 = gwp[base], g1 = gwp[base + cI];
      const float u0 = uwp[base], u1 = uwp[base + cI];
      const int di = (kpi >> 2) * 256 + nW * 4 + (kpi & 3);
      sG[di] = pack2(g0, g1);
      sU[di] = pack2(u0, u1);
    }
    __syncthreads();

    const bf16x8 af = *(const bf16x8*)&sA[(rw + (l & 15)) * 20 + (l >> 4) * 4];
    const int bi = ((l >> 4) * 64 + cw + (l & 15)) * 4;
    const bf16x8 bg0 = *(const bf16x8*)&sG[bi];
    const bf16x8 bg1 = *(const bf16x8*)&sG[bi + 64];
    const bf16x8 bu0 = *(const bf16x8*)&sU[bi];
    const bf16x8 bu1 = *(const bf16x8*)&sU[bi + 64];
    ag0 = __builtin_amdgcn_mfma_f32_16x16x32_bf16(af, bg0, ag0, 0, 0, 0);
    ag1 = __builtin_amdgcn_mfma_f32_16x16x32_bf16(af, bg1, ag1, 0, 0, 0);
    au0 = __builtin_amdgcn_mfma_f32_16x16x32_bf16(af, bu0, au0, 0, 0, 0);
    au1 = __builtin_amdgcn_mfma_f32_16x16x32_bf16(af, bu1, au1, 0, 0, 0);
    __syncthreads();
  }

  // epilogue: silu(g) * u -> bf16 act
#pragma unroll
  for (int ns = 0; ns < 2; ++ns) {
    const f32x4 g = ns ? ag1 : ag0;
    const f32x4 u = ns ? au1 : au0;
#pragma unroll
    for (int j = 0; j < 4; ++j) {
      const int row = rw + (l >> 4) * 4 + j;
      const int gr = mt * 32 + row;
      if (gr < n_e) {
        const float gv = g[j];
        const float val = (gv / (1.f + __expf(-gv))) * u[j];
        const int col = nb + cw + ns * 16 + (l & 15);
        act[(size_t)(off + gr) * cI + col] = (unsigned short)f2bf(val);
      }
    }
  }
}

// ------------------------------------------------------------------ down ----
__global__ __launch_bounds__(256) void down_kernel(
    const unsigned short* __restrict__ act, const float* __restrict__ dw,
    const int* __restrict__ offsets, const int* __restrict__ pair_token,
    const float* __restrict__ pair_w, float* __restrict__ out) {
  const int e = blockIdx.z;
  const int off = offsets[e];
  const int n_e = offsets[e + 1] - off;
  const int mt = blockIdx.x;
  if (mt * 32 >= n_e) return;
  const int nb = blockIdx.y * 64;
  const int tid = threadIdx.x;

  __shared__ unsigned sA[32 * 20];
  __shared__ unsigned sW[1024];

  const int rA = tid >> 3;   // 0..31
  const int kq = tid & 7;    // 4-bf16 slot
  const bool aok = (mt * 32 + rA) < n_e;
  const unsigned short* asrc = nullptr;
  if (aok) asrc = act + (size_t)(off + mt * 32 + rA) * cI + kq * 4;

  const float* dwp = dw + (size_t)e * cI * cH + nb;
  const int nW = tid & 63;
  const int kp0 = tid >> 6;

  const int w = tid >> 6, l = tid & 63;
  const int rw = (w >> 1) * 16, cw = (w & 1) * 32;
  f32x4 a0 = {0.f, 0.f, 0.f, 0.f}, a1 = {0.f, 0.f, 0.f, 0.f};

  for (int kt = 0; kt < cI / 32; ++kt) {
    uint2 v = make_uint2(0u, 0u);
    if (aok) v = *(const uint2*)(asrc + kt * 32);
    *(uint2*)&sA[rA * 20 + kq * 2] = v;
#pragma unroll
    for (int it = 0; it < 4; ++it) {
      const int kpi = kp0 + 4 * it;
      const size_t base = (size_t)(kt * 32 + 2 * kpi) * cH + nW;
      const float w0 = dwp[base], w1 = dwp[base + cH];
      sW[(kpi >> 2) * 256 + nW * 4 + (kpi & 3)] = pack2(w0, w1);
    }
    __syncthreads();

    const bf16x8 af = *(const bf16x8*)&sA[(rw + (l & 15)) * 20 + (l >> 4) * 4];
    const int bi = ((l >> 4) * 64 + cw + (l & 15)) * 4;
    const bf16x8 b0 = *(const bf16x8*)&sW[bi];
    const bf16x8 b1 = *(const bf16x8*)&sW[bi + 64];
    a0 = __builtin_amdgcn_mfma_f32_16x16x32_bf16(af, b0, a0, 0, 0, 0);
    a1 = __builtin_amdgcn_mfma_f32_16x16x32_bf16(af, b1, a1, 0, 0, 0);
    __syncthreads();
  }

#pragma unroll
  for (int j = 0; j < 4; ++j) {
    const int row = rw + (l >> 4) * 4 + j;
    const int gr = mt * 32 + row;
    if (gr < n_e) {
      const int pr = off + gr;
      const int t = pair_token[pr];
      const float wgt = pair_w[pr];
      const int colb = nb + cw + (l & 15);
      atomicAdd(out + (size_t)t * cH + colb, wgt * a0[j]);
      atomicAdd(out + (size_t)t * cH + colb + 16, wgt * a1[j]);
    }
  }
}

// ---------------------------------------------------------------- launch ----
extern "C" void kernel_launch(void* const* d_in, const int* in_sizes, int n_in,
                              void* d_out, int out_size, void* d_ws,
                              size_t ws_size, hipStream_t stream) {
  (void)in_sizes; (void)n_in; (void)out_size; (void)ws_size;
  const float* x = (const float*)d_in[0];
  const float* Wg = (const float*)d_in[1];
  const float* gw = (const float*)d_in[2];
  const float* uw = (const float*)d_in[3];
  const float* dw = (const float*)d_in[4];
  float* out = (float*)d_out;

  char* ws = (char*)d_ws;
  int* counts     = (int*)(ws + 0);          // 16 ints
  int* cursor     = (int*)(ws + 64);         // 16 ints
  int* offsets    = (int*)(ws + 128);        // 17 ints
  int* topk_id    = (int*)(ws + 256);        // 4096 ints
  float* topk_w   = (float*)(ws + 256 + 16384);
  int* pair_token = (int*)(ws + 256 + 32768);
  float* pair_w   = (float*)(ws + 256 + 49152);
  unsigned short* act = (unsigned short*)(ws + 65792);   // 4096*2816 bf16

  hipMemsetAsync(ws, 0, 128, stream);                        // counts+cursor
  hipMemsetAsync(d_out, 0, (size_t)cT * cH * sizeof(float), stream);

  router_kernel<<<cT, 64, 0, stream>>>(x, Wg, topk_id, topk_w, counts);
  scan_kernel<<<1, 1, 0, stream>>>(counts, offsets);
  scatter_kernel<<<cT * cK / 256, 256, 0, stream>>>(topk_id, topk_w, offsets,
                                                    cursor, pair_token, pair_w);
  gateup_kernel<<<dim3(32, cI / 64, cE), 256, 0, stream>>>(x, gw, uw, offsets,
                                                           pair_token, act);
  down_kernel<<<dim3(32, cH / 64, cE), 256, 0, stream>>>(act, dw, offsets,
                                                         pair_token, pair_w, out);
}

// Round 2
// 454.173 us; speedup vs baseline: 3.1953x; 3.1953x over previous
//
#include <hip/hip_runtime.h>

static constexpr int cT = 1024;   // tokens
static constexpr int cH = 1024;   // hidden
static constexpr int cI = 2816;   // intermediate
static constexpr int cE = 16;     // experts
static constexpr int cK = 4;      // top-k

typedef __attribute__((ext_vector_type(8))) short bf16x8;
typedef __attribute__((ext_vector_type(4))) float f32x4;
typedef __attribute__((ext_vector_type(4))) unsigned uint4v;
typedef __attribute__((ext_vector_type(2))) unsigned uint2v;

__device__ __forceinline__ unsigned f2bf(float f) {
  unsigned u = __float_as_uint(f);
  return (u + 0x7FFFu + ((u >> 16) & 1u)) >> 16;   // RNE f32->bf16
}
__device__ __forceinline__ unsigned pack2(float lo, float hi) {
  return f2bf(lo) | (f2bf(hi) << 16);
}

// ------------------------------------------------------------- x -> bf16 ----
__global__ __launch_bounds__(256) void xcast_kernel(
    const float* __restrict__ x, unsigned short* __restrict__ xb) {
  const int i = blockIdx.x * 256 + threadIdx.x;       // 131072 threads, 8 elems each
  const float4* xv = (const float4*)x;
  const float4 a = xv[i * 2], b = xv[i * 2 + 1];
  uint4v o;
  o.x = pack2(a.x, a.y); o.y = pack2(a.z, a.w);
  o.z = pack2(b.x, b.y); o.w = pack2(b.z, b.w);
  ((uint4v*)xb)[i] = o;
}

// ---------------------------------------------------------------- router ----
__global__ __launch_bounds__(64) void router_kernel(
    const float* __restrict__ x, const float* __restrict__ Wg,
    int* __restrict__ topk_id, float* __restrict__ topk_w,
    int* __restrict__ counts) {
  const int t = blockIdx.x;
  const int l = threadIdx.x;

  float xa[16];
#pragma unroll
  for (int i = 0; i < 16; ++i) xa[i] = x[(size_t)t * cH + l + 64 * i];

  float lg[16];
#pragma unroll
  for (int e = 0; e < 16; ++e) {
    float s = 0.f;
#pragma unroll
    for (int i = 0; i < 16; ++i) s += xa[i] * Wg[(size_t)e * cH + l + 64 * i];
#pragma unroll
    for (int d = 1; d < 64; d <<= 1) s += __shfl_xor(s, d);
    lg[e] = s;
  }

  if (l == 0) {
    int ids[4]; float vals[4];
    unsigned taken = 0;
#pragma unroll
    for (int j = 0; j < 4; ++j) {
      float m = -1e30f; int mi = 0;
#pragma unroll
      for (int e = 0; e < 16; ++e) {
        bool better = !((taken >> e) & 1u) && lg[e] > m;
        if (better) { m = lg[e]; mi = e; }
      }
      taken |= 1u << mi; ids[j] = mi; vals[j] = m;
    }
    const float mx = vals[0];
    float s = 0.f;
#pragma unroll
    for (int j = 0; j < 4; ++j) { vals[j] = __expf(vals[j] - mx); s += vals[j]; }
    const float inv = 1.f / s;
#pragma unroll
    for (int j = 0; j < 4; ++j) {
      topk_id[t * 4 + j] = ids[j];
      topk_w[t * 4 + j] = vals[j] * inv;
      atomicAdd(&counts[ids[j]], 1);
    }
  }
}

__global__ void scan_kernel(const int* __restrict__ counts,
                            int* __restrict__ offsets) {
  if (threadIdx.x == 0 && blockIdx.x == 0) {
    int acc = 0;
    for (int e = 0; e < cE; ++e) { offsets[e] = acc; acc += counts[e]; }
    offsets[cE] = acc;
  }
}

__global__ __launch_bounds__(256) void scatter_kernel(
    const int* __restrict__ topk_id, const float* __restrict__ topk_w,
    const int* __restrict__ offsets, int* __restrict__ cursor,
    int* __restrict__ pair_token, float* __restrict__ pair_w) {
  const int i = blockIdx.x * 256 + threadIdx.x;   // 0..4095
  const int t = i >> 2;
  const int e = topk_id[i];
  const int pos = offsets[e] + atomicAdd(&cursor[e], 1);
  pair_token[pos] = t;
  pair_w[pos] = topk_w[i];
}

// ---------------------------------------------------------------- gate+up ---
// Block = (64-col strip of I, expert). Loops over all the expert's rows in
// 256-row chunks held in registers; weights stream from HBM exactly once per
// block. A-fragments gathered per-lane from bf16 x (L2-resident). B staged
// f32->bf16 into LDS [k/8][n][k%8] with conflict-free b128 writes (col=q+16j).
__global__ __launch_bounds__(256, 2) void gateup_kernel(
    const unsigned short* __restrict__ xb, const float* __restrict__ gw,
    const float* __restrict__ uw, const int* __restrict__ offsets,
    const int* __restrict__ pair_token, unsigned short* __restrict__ act) {
  const int e = blockIdx.y;
  const int off = offsets[e];
  const int n_e = offsets[e + 1] - off;
  if (n_e <= 0) return;
  const int nb = blockIdx.x * 64;
  const int tid = threadIdx.x;
  const int l = tid & 63, w = tid >> 6;
  const int wm = w * 64;                       // wave's row base in chunk

  __shared__ unsigned sB[2 * 2048];            // [mat][g0..7][c0..63] quads
  __shared__ int tokl[256];

  const int mat = tid >> 7;                    // 0 = gate, 1 = up
  const int bg_ = (tid >> 4) & 7;              // k-group (8 rows)
  const int bq  = tid & 15;                    // col = bq + 16*j
  const float* wp = (mat ? uw : gw) + (size_t)e * cH * cI + nb;

  for (int m0 = 0; m0 < n_e; m0 += 256) {
    const int rows = min(256, n_e - m0);
    tokl[tid] = pair_token[off + m0 + min(tid, rows - 1)];
    __syncthreads();

    const unsigned short* ap[4];
#pragma unroll
    for (int mi = 0; mi < 4; ++mi) {
      const int r = min(wm + mi * 16 + (l & 15), rows - 1);
      ap[mi] = xb + (size_t)tokl[r] * cH + (l >> 4) * 8;
    }

    f32x4 ag[4][4], au[4][4];
#pragma unroll
    for (int mi = 0; mi < 4; ++mi)
#pragma unroll
      for (int ni = 0; ni < 4; ++ni) {
        ag[mi][ni].x = 0.f; ag[mi][ni].y = 0.f; ag[mi][ni].z = 0.f; ag[mi][ni].w = 0.f;
        au[mi][ni].x = 0.f; au[mi][ni].y = 0.f; au[mi][ni].z = 0.f; au[mi][ni].w = 0.f;
      }

    for (int kt = 0; kt < cH / 64; ++kt) {
      // A fragments straight to registers (per-lane 16B gathers, L2-hit)
      bf16x8 av[4][2];
#pragma unroll
      for (int mi = 0; mi < 4; ++mi)
#pragma unroll
        for (int ks = 0; ks < 2; ++ks)
          av[mi][ks] = *(const bf16x8*)(ap[mi] + kt * 64 + ks * 32);

      // B staging: 8 rows x 4 cols per thread, transpose-pack f32->bf16
#pragma unroll
      for (int j = 0; j < 4; ++j) {
        const int c = bq + 16 * j;
        const float* p = wp + (size_t)(kt * 64 + bg_ * 8) * cI + c;
        const float f0 = p[0];
        const float f1 = p[(size_t)cI];
        const float f2 = p[(size_t)2 * cI];
        const float f3 = p[(size_t)3 * cI];
        const float f4 = p[(size_t)4 * cI];
        const float f5 = p[(size_t)5 * cI];
        const float f6 = p[(size_t)6 * cI];
        const float f7 = p[(size_t)7 * cI];
        uint4v P;
        P.x = pack2(f0, f1); P.y = pack2(f2, f3);
        P.z = pack2(f4, f5); P.w = pack2(f6, f7);
        *(uint4v*)&sB[mat * 2048 + (bg_ * 64 + c) * 4] = P;
      }
      __syncthreads();

#pragma unroll
      for (int ks = 0; ks < 2; ++ks) {
        const int gidx = ks * 4 + (l >> 4);
#pragma unroll
        for (int ni = 0; ni < 4; ++ni) {
          const int bi = (gidx * 64 + ni * 16 + (l & 15)) * 4;
          const bf16x8 bgf = *(const bf16x8*)&sB[bi];
          const bf16x8 buf_ = *(const bf16x8*)&sB[2048 + bi];
#pragma unroll
          for (int mi = 0; mi < 4; ++mi) {
            ag[mi][ni] = __builtin_amdgcn_mfma_f32_16x16x32_bf16(av[mi][ks], bgf, ag[mi][ni], 0, 0, 0);
            au[mi][ni] = __builtin_amdgcn_mfma_f32_16x16x32_bf16(av[mi][ks], buf_, au[mi][ni], 0, 0, 0);
          }
        }
      }
      __syncthreads();
    }

    // epilogue: silu(g)*u -> bf16 act
#pragma unroll
    for (int mi = 0; mi < 4; ++mi)
#pragma unroll
      for (int j = 0; j < 4; ++j) {
        const int er = m0 + wm + mi * 16 + (l >> 4) * 4 + j;
        if (er < n_e) {
#pragma unroll
          for (int ni = 0; ni < 4; ++ni) {
            const float g = ag[mi][ni][j], u = au[mi][ni][j];
            const float v = (g / (1.f + __expf(-g))) * u;
            act[(size_t)(off + er) * cI + nb + ni * 16 + (l & 15)] =
                (unsigned short)f2bf(v);
          }
        }
      }
  }
}

// ------------------------------------------------------------------ down ----
__global__ __launch_bounds__(256, 2) void down_kernel(
    const unsigned short* __restrict__ act, const float* __restrict__ dw,
    const int* __restrict__ offsets, const int* __restrict__ pair_token,
    const float* __restrict__ pair_w, float* __restrict__ out) {
  const int e = blockIdx.y;
  const int off = offsets[e];
  const int n_e = offsets[e + 1] - off;
  if (n_e <= 0) return;
  const int nb = blockIdx.x * 64;
  const int tid = threadIdx.x;
  const int l = tid & 63, w = tid >> 6;
  const int wm = w * 80;                       // CHUNK=320: wave owns 80 rows

  __shared__ unsigned sB[2048];

  const int bg_ = tid >> 5;                    // k-group
  const int bq  = (tid >> 1) & 15;             // col = bq + 16*j
  const int bh  = tid & 1;                     // row-half within group
  const float* wp = dw + (size_t)e * cI * cH + nb;

  for (int m0 = 0; m0 < n_e; m0 += 320) {
    const unsigned short* ap[5];
#pragma unroll
    for (int mi = 0; mi < 5; ++mi) {
      const int r = min(m0 + wm + mi * 16 + (l & 15), n_e - 1);
      ap[mi] = act + (size_t)(off + r) * cI + (l >> 4) * 8;
    }

    f32x4 acc[5][4];
#pragma unroll
    for (int mi = 0; mi < 5; ++mi)
#pragma unroll
      for (int ni = 0; ni < 4; ++ni) {
        acc[mi][ni].x = 0.f; acc[mi][ni].y = 0.f;
        acc[mi][ni].z = 0.f; acc[mi][ni].w = 0.f;
      }

    for (int kt = 0; kt < cI / 64; ++kt) {
      bf16x8 av[5][2];
#pragma unroll
      for (int mi = 0; mi < 5; ++mi)
#pragma unroll
        for (int ks = 0; ks < 2; ++ks)
          av[mi][ks] = *(const bf16x8*)(ap[mi] + kt * 64 + ks * 32);

#pragma unroll
      for (int j = 0; j < 4; ++j) {
        const int c = bq + 16 * j;
        const float* p = wp + (size_t)(kt * 64 + bg_ * 8 + bh * 4) * cH + c;
        const float f0 = p[0];
        const float f1 = p[(size_t)cH];
        const float f2 = p[(size_t)2 * cH];
        const float f3 = p[(size_t)3 * cH];
        uint2v P;
        P.x = pack2(f0, f1); P.y = pack2(f2, f3);
        *(uint2v*)((char*)sB + (bg_ * 64 + c) * 16 + bh * 8) = P;
      }
      __syncthreads();

#pragma unroll
      for (int ks = 0; ks < 2; ++ks) {
        const int gidx = ks * 4 + (l >> 4);
#pragma unroll
        for (int ni = 0; ni < 4; ++ni) {
          const bf16x8 b = *(const bf16x8*)&sB[(gidx * 64 + ni * 16 + (l & 15)) * 4];
#pragma unroll
          for (int mi = 0; mi < 5; ++mi)
            acc[mi][ni] = __builtin_amdgcn_mfma_f32_16x16x32_bf16(av[mi][ks], b, acc[mi][ni], 0, 0, 0);
        }
      }
      __syncthreads();
    }

#pragma unroll
    for (int mi = 0; mi < 5; ++mi)
#pragma unroll
      for (int j = 0; j < 4; ++j) {
        const int er = m0 + wm + mi * 16 + (l >> 4) * 4 + j;
        if (er < n_e) {
          const int pr = off + er;
          const int t = pair_token[pr];
          const float wgt = pair_w[pr];
#pragma unroll
          for (int ni = 0; ni < 4; ++ni)
            atomicAdd(out + (size_t)t * cH + nb + ni * 16 + (l & 15),
                      wgt * acc[mi][ni][j]);
        }
      }
  }
}

// ---------------------------------------------------------------- launch ----
extern "C" void kernel_launch(void* const* d_in, const int* in_sizes, int n_in,
                              void* d_out, int out_size, void* d_ws,
                              size_t ws_size, hipStream_t stream) {
  (void)in_sizes; (void)n_in; (void)out_size; (void)ws_size;
  const float* x = (const float*)d_in[0];
  const float* Wg = (const float*)d_in[1];
  const float* gw = (const float*)d_in[2];
  const float* uw = (const float*)d_in[3];
  const float* dw = (const float*)d_in[4];
  float* out = (float*)d_out;

  char* ws = (char*)d_ws;
  int* counts     = (int*)(ws + 0);            // 16 ints
  int* cursor     = (int*)(ws + 64);           // 16 ints
  int* offsets    = (int*)(ws + 128);          // 17 ints
  int* topk_id    = (int*)(ws + 256);          // 4096 ints
  float* topk_w   = (float*)(ws + 256 + 16384);
  int* pair_token = (int*)(ws + 256 + 32768);
  float* pair_w   = (float*)(ws + 256 + 49152);
  unsigned short* act = (unsigned short*)(ws + 65792);            // 4096*2816 bf16
  unsigned short* xb  = (unsigned short*)(ws + 65792 + (size_t)4096 * 2816 * 2);

  hipMemsetAsync(ws, 0, 128, stream);                        // counts+cursor
  hipMemsetAsync(d_out, 0, (size_t)cT * cH * sizeof(float), stream);

  xcast_kernel<<<cT * cH / (256 * 8), 256, 0, stream>>>(x, xb);
  router_kernel<<<cT, 64, 0, stream>>>(x, Wg, topk_id, topk_w, counts);
  scan_kernel<<<1, 1, 0, stream>>>(counts, offsets);
  scatter_kernel<<<cT * cK / 256, 256, 0, stream>>>(topk_id, topk_w, offsets,
                                                    cursor, pair_token, pair_w);
  gateup_kernel<<<dim3(cI / 64, cE), 256, 0, stream>>>(xb, gw, uw, offsets,
                                                       pair_token, act);
  down_kernel<<<dim3(cH / 64, cE), 256, 0, stream>>>(act, dw, offsets,
                                                     pair_token, pair_w, out);
}

// Round 3
// 408.822 us; speedup vs baseline: 3.5497x; 1.1109x over previous
//
#include <hip/hip_runtime.h>

static constexpr int cT = 1024;   // tokens
static constexpr int cH = 1024;   // hidden
static constexpr int cI = 2816;   // intermediate
static constexpr int cE = 16;     // experts
static constexpr int cK = 4;      // top-k

typedef __attribute__((ext_vector_type(8))) short bf16x8;
typedef __attribute__((ext_vector_type(4))) float f32x4;
typedef __attribute__((ext_vector_type(2))) unsigned uint2v;
typedef __attribute__((ext_vector_type(4))) unsigned uint4v;

__device__ __forceinline__ unsigned f2bf(float f) {
  unsigned u = __float_as_uint(f);
  return (u + 0x7FFFu + ((u >> 16) & 1u)) >> 16;   // RNE f32->bf16
}
__device__ __forceinline__ unsigned pack2(float lo, float hi) {
  return f2bf(lo) | (f2bf(hi) << 16);
}

// Two ds_read_b64 (8B-aligned; stride-34-uint layout is not 16B-aligned).
__device__ __forceinline__ bf16x8 ld_bfrag(const unsigned* p) {
  union { uint2v d[2]; bf16x8 v; } r;
  r.d[0] = *(const uint2v*)p;
  r.d[1] = *(const uint2v*)(p + 2);
  return r.v;
}

// ------------------------------------------------------------- x -> bf16 ----
__global__ __launch_bounds__(256) void xcast_kernel(
    const float* __restrict__ x, unsigned short* __restrict__ xb) {
  const int i = blockIdx.x * 256 + threadIdx.x;
  const float4* xv = (const float4*)x;
  const float4 a = xv[i * 2], b = xv[i * 2 + 1];
  uint4v o;
  o.x = pack2(a.x, a.y); o.y = pack2(a.z, a.w);
  o.z = pack2(b.x, b.y); o.w = pack2(b.z, b.w);
  ((uint4v*)xb)[i] = o;
}

// ---------------------------------------------------------------- router ----
__global__ __launch_bounds__(64) void router_kernel(
    const float* __restrict__ x, const float* __restrict__ Wg,
    int* __restrict__ topk_id, float* __restrict__ topk_w,
    int* __restrict__ counts) {
  const int t = blockIdx.x;
  const int l = threadIdx.x;

  float xa[16];
#pragma unroll
  for (int i = 0; i < 16; ++i) xa[i] = x[(size_t)t * cH + l + 64 * i];

  float lg[16];
#pragma unroll
  for (int e = 0; e < 16; ++e) {
    float s = 0.f;
#pragma unroll
    for (int i = 0; i < 16; ++i) s += xa[i] * Wg[(size_t)e * cH + l + 64 * i];
#pragma unroll
    for (int d = 1; d < 64; d <<= 1) s += __shfl_xor(s, d);
    lg[e] = s;
  }

  if (l == 0) {
    int ids[4]; float vals[4];
    unsigned taken = 0;
#pragma unroll
    for (int j = 0; j < 4; ++j) {
      float m = -1e30f; int mi = 0;
#pragma unroll
      for (int e = 0; e < 16; ++e) {
        bool better = !((taken >> e) & 1u) && lg[e] > m;
        if (better) { m = lg[e]; mi = e; }
      }
      taken |= 1u << mi; ids[j] = mi; vals[j] = m;
    }
    const float mx = vals[0];
    float s = 0.f;
#pragma unroll
    for (int j = 0; j < 4; ++j) { vals[j] = __expf(vals[j] - mx); s += vals[j]; }
    const float inv = 1.f / s;
#pragma unroll
    for (int j = 0; j < 4; ++j) {
      topk_id[t * 4 + j] = ids[j];
      topk_w[t * 4 + j] = vals[j] * inv;
      atomicAdd(&counts[ids[j]], 1);
    }
  }
}

__global__ void scan_kernel(const int* __restrict__ counts,
                            int* __restrict__ offsets) {
  if (threadIdx.x == 0 && blockIdx.x == 0) {
    int acc = 0;
    for (int e = 0; e < cE; ++e) { offsets[e] = acc; acc += counts[e]; }
    offsets[cE] = acc;
  }
}

__global__ __launch_bounds__(256) void scatter_kernel(
    const int* __restrict__ topk_id, const int* __restrict__ offsets,
    int* __restrict__ cursor, int* __restrict__ pair_token,
    int* __restrict__ pair_pos) {
  const int i = blockIdx.x * 256 + threadIdx.x;   // 0..4095
  const int t = i >> 2;
  const int e = topk_id[i];
  const int pos = offsets[e] + atomicAdd(&cursor[e], 1);
  pair_token[pos] = t;
  pair_pos[i] = pos;
}

// ---------------------------------------------------------------- gate+up ---
// Block = (64-col strip, 128-row chunk, expert). Sibling chunk-blocks of one
// strip run concurrently -> weight re-reads hit L2/L3. Double-buffered LDS
// B-staging with float4-coalesced loads (4 rows x float4 per thread) packed
// f32->bf16 into [n][kpair] stride-34 layout (conflict-free b64 writes+reads).
__global__ __launch_bounds__(256, 3) void gateup_kernel(
    const unsigned short* __restrict__ xb, const float* __restrict__ gw,
    const float* __restrict__ uw, const int* __restrict__ offsets,
    const int* __restrict__ pair_token, unsigned short* __restrict__ act) {
  const int e = blockIdx.y;
  const int off = offsets[e];
  const int n_e = offsets[e + 1] - off;
  const int strip = blockIdx.x / 3;
  const int c0 = (blockIdx.x % 3) * 128;
  if (c0 >= n_e) return;
  const int nb = strip * 64;
  const int tid = threadIdx.x, l = tid & 63, w = tid >> 6;

  __shared__ unsigned sB[2][2][2176];   // [buf][mat][n*34 + kpair]
  __shared__ int tokl[128];

  const int sa = tid >> 4;              // row-quad 0..15
  const int sc = tid & 15;              // col-quad 0..15
  const float* gb = gw + (size_t)e * cH * cI + nb + sc * 4;
  const float* ub = uw + (size_t)e * cH * cI + nb + sc * 4;

  for (int m0 = c0; m0 < n_e; m0 += 384) {
    if (tid < 128) tokl[tid] = pair_token[off + min(m0 + tid, n_e - 1)];
    __syncthreads();
    const int rows = min(128, n_e - m0);

    const unsigned short* ap[2];
#pragma unroll
    for (int mi = 0; mi < 2; ++mi) {
      const int idx = min(w * 32 + mi * 16 + (l & 15), rows - 1);
      ap[mi] = xb + (size_t)tokl[idx] * cH + (l >> 4) * 8;
    }

    f32x4 ag[2][4], au[2][4];
#pragma unroll
    for (int mi = 0; mi < 2; ++mi)
#pragma unroll
      for (int ni = 0; ni < 4; ++ni) {
        ag[mi][ni] = (f32x4){0.f, 0.f, 0.f, 0.f};
        au[mi][ni] = (f32x4){0.f, 0.f, 0.f, 0.f};
      }

    float4 rg[4], ru[4];
#pragma unroll
    for (int j = 0; j < 4; ++j) {
      rg[j] = *(const float4*)(gb + (size_t)(sa * 4 + j) * cI);
      ru[j] = *(const float4*)(ub + (size_t)(sa * 4 + j) * cI);
    }

    for (int kt = 0; kt < 16; ++kt) {
      const int cur = kt & 1;
      const int wbase = (sc * 4) * 34 + sa * 2;
#pragma unroll
      for (int i = 0; i < 4; ++i) {
        uint2v pg, pu;
        pg.x = pack2(rg[0][i], rg[1][i]); pg.y = pack2(rg[2][i], rg[3][i]);
        pu.x = pack2(ru[0][i], ru[1][i]); pu.y = pack2(ru[2][i], ru[3][i]);
        *(uint2v*)&sB[cur][0][wbase + i * 34] = pg;
        *(uint2v*)&sB[cur][1][wbase + i * 34] = pu;
      }
      if (kt + 1 < 16) {
#pragma unroll
        for (int j = 0; j < 4; ++j) {
          rg[j] = *(const float4*)(gb + (size_t)((kt + 1) * 64 + sa * 4 + j) * cI);
          ru[j] = *(const float4*)(ub + (size_t)((kt + 1) * 64 + sa * 4 + j) * cI);
        }
      }
      __syncthreads();   // single barrier per tile; dbuf parity makes it safe

      bf16x8 av[2][2];
#pragma unroll
      for (int mi = 0; mi < 2; ++mi)
#pragma unroll
        for (int ks = 0; ks < 2; ++ks)
          av[mi][ks] = *(const bf16x8*)(ap[mi] + kt * 64 + ks * 32);

#pragma unroll
      for (int ks = 0; ks < 2; ++ks)
#pragma unroll
        for (int ni = 0; ni < 4; ++ni) {
          const int base = ((l & 15) + 16 * ni) * 34 + (l >> 4) * 4 + 16 * ks;
          const bf16x8 bg = ld_bfrag(&sB[cur][0][base]);
          const bf16x8 bu = ld_bfrag(&sB[cur][1][base]);
#pragma unroll
          for (int mi = 0; mi < 2; ++mi) {
            ag[mi][ni] = __builtin_amdgcn_mfma_f32_16x16x32_bf16(av[mi][ks], bg, ag[mi][ni], 0, 0, 0);
            au[mi][ni] = __builtin_amdgcn_mfma_f32_16x16x32_bf16(av[mi][ks], bu, au[mi][ni], 0, 0, 0);
          }
        }
    }

    // epilogue: silu(g)*u -> bf16 act
#pragma unroll
    for (int mi = 0; mi < 2; ++mi)
#pragma unroll
      for (int j = 0; j < 4; ++j) {
        const int er = m0 + w * 32 + mi * 16 + (l >> 4) * 4 + j;
        if (er < n_e) {
#pragma unroll
          for (int ni = 0; ni < 4; ++ni) {
            const float g = ag[mi][ni][j], u = au[mi][ni][j];
            const float v = (g / (1.f + __expf(-g))) * u;
            act[(size_t)(off + er) * cI + nb + ni * 16 + (l & 15)] =
                (unsigned short)f2bf(v);
          }
        }
      }
  }
}

// ------------------------------------------------------------------ down ----
__global__ __launch_bounds__(256, 4) void down_kernel(
    const unsigned short* __restrict__ act, const float* __restrict__ dw,
    const int* __restrict__ offsets, float* __restrict__ yp) {
  const int e = blockIdx.y;
  const int off = offsets[e];
  const int n_e = offsets[e + 1] - off;
  const int strip = blockIdx.x / 3;
  const int c0 = (blockIdx.x % 3) * 128;
  if (c0 >= n_e) return;
  const int nb = strip * 64;
  const int tid = threadIdx.x, l = tid & 63, w = tid >> 6;

  __shared__ unsigned sB[2][2176];

  const int sa = tid >> 4, sc = tid & 15;
  const float* db = dw + (size_t)e * cI * cH + nb + sc * 4;

  for (int m0 = c0; m0 < n_e; m0 += 384) {
    const int rows = min(128, n_e - m0);
    const unsigned short* ap[2];
#pragma unroll
    for (int mi = 0; mi < 2; ++mi) {
      const int r = min(m0 + w * 32 + mi * 16 + (l & 15), m0 + rows - 1);
      ap[mi] = act + (size_t)(off + r) * cI + (l >> 4) * 8;
    }

    f32x4 acc[2][4];
#pragma unroll
    for (int mi = 0; mi < 2; ++mi)
#pragma unroll
      for (int ni = 0; ni < 4; ++ni) acc[mi][ni] = (f32x4){0.f, 0.f, 0.f, 0.f};

    float4 rd[4];
#pragma unroll
    for (int j = 0; j < 4; ++j)
      rd[j] = *(const float4*)(db + (size_t)(sa * 4 + j) * cH);

    for (int kt = 0; kt < cI / 64; ++kt) {
      const int cur = kt & 1;
      const int wbase = (sc * 4) * 34 + sa * 2;
#pragma unroll
      for (int i = 0; i < 4; ++i) {
        uint2v p;
        p.x = pack2(rd[0][i], rd[1][i]); p.y = pack2(rd[2][i], rd[3][i]);
        *(uint2v*)&sB[cur][wbase + i * 34] = p;
      }
      if (kt + 1 < cI / 64) {
#pragma unroll
        for (int j = 0; j < 4; ++j)
          rd[j] = *(const float4*)(db + (size_t)((kt + 1) * 64 + sa * 4 + j) * cH);
      }
      __syncthreads();

      bf16x8 av[2][2];
#pragma unroll
      for (int mi = 0; mi < 2; ++mi)
#pragma unroll
        for (int ks = 0; ks < 2; ++ks)
          av[mi][ks] = *(const bf16x8*)(ap[mi] + kt * 64 + ks * 32);

#pragma unroll
      for (int ks = 0; ks < 2; ++ks)
#pragma unroll
        for (int ni = 0; ni < 4; ++ni) {
          const int base = ((l & 15) + 16 * ni) * 34 + (l >> 4) * 4 + 16 * ks;
          const bf16x8 b = ld_bfrag(&sB[cur][base]);
#pragma unroll
          for (int mi = 0; mi < 2; ++mi)
            acc[mi][ni] = __builtin_amdgcn_mfma_f32_16x16x32_bf16(av[mi][ks], b, acc[mi][ni], 0, 0, 0);
        }
    }

#pragma unroll
    for (int mi = 0; mi < 2; ++mi)
#pragma unroll
      for (int j = 0; j < 4; ++j) {
        const int er = m0 + w * 32 + mi * 16 + (l >> 4) * 4 + j;
        if (er < n_e) {
#pragma unroll
          for (int ni = 0; ni < 4; ++ni)
            yp[(size_t)(off + er) * cH + nb + ni * 16 + (l & 15)] = acc[mi][ni][j];
        }
      }
  }
}

// --------------------------------------------------------------- combine ----
__global__ __launch_bounds__(256) void combine_kernel(
    const float* __restrict__ yp, const int* __restrict__ pair_pos,
    const float* __restrict__ topk_w, float* __restrict__ out) {
  const int t = blockIdx.x;
  const int cb = threadIdx.x * 4;
  float4 s = make_float4(0.f, 0.f, 0.f, 0.f);
#pragma unroll
  for (int j = 0; j < 4; ++j) {
    const int pos = pair_pos[t * 4 + j];
    const float wj = topk_w[t * 4 + j];
    const float4 v = *(const float4*)(yp + (size_t)pos * cH + cb);
    s.x += wj * v.x; s.y += wj * v.y; s.z += wj * v.z; s.w += wj * v.w;
  }
  *(float4*)(out + (size_t)t * cH + cb) = s;
}

// ---------------------------------------------------------------- launch ----
extern "C" void kernel_launch(void* const* d_in, const int* in_sizes, int n_in,
                              void* d_out, int out_size, void* d_ws,
                              size_t ws_size, hipStream_t stream) {
  (void)in_sizes; (void)n_in; (void)out_size; (void)ws_size;
  const float* x = (const float*)d_in[0];
  const float* Wg = (const float*)d_in[1];
  const float* gw = (const float*)d_in[2];
  const float* uw = (const float*)d_in[3];
  const float* dw = (const float*)d_in[4];
  float* out = (float*)d_out;

  char* ws = (char*)d_ws;
  int* counts     = (int*)(ws + 0);          // 16
  int* cursor     = (int*)(ws + 64);         // 16
  int* offsets    = (int*)(ws + 128);        // 17
  int* topk_id    = (int*)(ws + 256);        // 4096
  float* topk_w   = (float*)(ws + 256 + 16384);
  int* pair_token = (int*)(ws + 256 + 32768);
  int* pair_pos   = (int*)(ws + 256 + 49152);
  unsigned short* act = (unsigned short*)(ws + 65792);           // 23.07 MB
  unsigned short* xb  = (unsigned short*)(ws + 65792 + (size_t)4096 * 2816 * 2);
  float* yp = (float*)(ws + 65792 + (size_t)4096 * 2816 * 2 + (size_t)cT * cH * 2);

  hipMemsetAsync(ws, 0, 128, stream);        // counts + cursor

  xcast_kernel<<<cT * cH / (256 * 8), 256, 0, stream>>>(x, xb);
  router_kernel<<<cT, 64, 0, stream>>>(x, Wg, topk_id, topk_w, counts);
  scan_kernel<<<1, 1, 0, stream>>>(counts, offsets);
  scatter_kernel<<<cT * cK / 256, 256, 0, stream>>>(topk_id, offsets, cursor,
                                                    pair_token, pair_pos);
  gateup_kernel<<<dim3(44 * 3, cE), 256, 0, stream>>>(xb, gw, uw, offsets,
                                                      pair_token, act);
  down_kernel<<<dim3(16 * 3, cE), 256, 0, stream>>>(act, dw, offsets, yp);
  combine_kernel<<<cT, 256, 0, stream>>>(yp, pair_pos, topk_w, out);
}